// Round 1
// baseline (306.275 us; speedup 1.0000x reference)
//
#include <hip/hip_runtime.h>
#include <math.h>

#define NTOK 4096   // tokens (B)
#define NDIM 1024   // per-tensor feature dim (D)
#define NEXP 64     // experts (E)
#define KTOT 2048   // concat dim (2D)
#define KC   512    // K chunk per GEMM block
#define NKC  4      // number of K chunks
#define TB   32     // tokens per GEMM block

// ---------------------------------------------------------------------------
// Kernel 1: per-expert squared norms ||w_e||^2  (64 blocks x 256 threads)
// ---------------------------------------------------------------------------
__global__ __launch_bounds__(256) void expert_norms(const float* __restrict__ W,
                                                    float* __restrict__ nrm) {
    const int e = blockIdx.x;
    const float* row = W + (size_t)e * KTOT;
    float s = 0.f;
    for (int k = threadIdx.x * 4; k < KTOT; k += 256 * 4) {
        float4 v = *reinterpret_cast<const float4*>(row + k);
        s = fmaf(v.x, v.x, fmaf(v.y, v.y, fmaf(v.z, v.z, fmaf(v.w, v.w, s))));
    }
    #pragma unroll
    for (int off = 32; off > 0; off >>= 1) s += __shfl_down(s, off, 64);
    __shared__ float red[4];
    const int lane = threadIdx.x & 63, wv = threadIdx.x >> 6;
    if (lane == 0) red[wv] = s;
    __syncthreads();
    if (threadIdx.x == 0) nrm[e] = (red[0] + red[1]) + (red[2] + red[3]);
}

// ---------------------------------------------------------------------------
// Kernel 2: split-K GEMM  Gp[kc][token][e] = sum_{k in chunk} x[token][k]*W[e][k]
// plus per-chunk ||x||^2 partials.  Lane layout: 32 tokens x 8 expert-octets.
// grid = (NTOK/TB, NKC), block = 256.
// ---------------------------------------------------------------------------
__global__ __launch_bounds__(256) void dist_gemm(const float* __restrict__ t1,
                                                 const float* __restrict__ t2,
                                                 const float* __restrict__ W,
                                                 float* __restrict__ Gp,
                                                 float* __restrict__ Cp) {
    const int tl = threadIdx.x >> 3;      // 0..31 local token
    const int g  = threadIdx.x & 7;       // expert octet: experts g*8 .. g*8+7
    const int token = blockIdx.x * TB + tl;
    const int kc = blockIdx.y;            // 0..3
    const int kbase = kc * KC;
    // Each 512-wide K chunk lies entirely inside t1 (k<1024) or t2.
    const float* xrow = (kbase < NDIM)
        ? (t1 + (size_t)token * NDIM + kbase)
        : (t2 + (size_t)token * NDIM + (kbase - NDIM));
    const float* wrow = W + (size_t)(g * 8) * KTOT + kbase;

    float acc[8];
    #pragma unroll
    for (int j = 0; j < 8; ++j) acc[j] = 0.f;
    float ss = 0.f;

    for (int k = 0; k < KC; k += 4) {
        const float4 xv = *reinterpret_cast<const float4*>(xrow + k);
        ss = fmaf(xv.x, xv.x, fmaf(xv.y, xv.y, fmaf(xv.z, xv.z, fmaf(xv.w, xv.w, ss))));
        #pragma unroll
        for (int j = 0; j < 8; ++j) {
            const float4 wv = *reinterpret_cast<const float4*>(wrow + (size_t)j * KTOT + k);
            acc[j] = fmaf(xv.x, wv.x, fmaf(xv.y, wv.y, fmaf(xv.z, wv.z, fmaf(xv.w, wv.w, acc[j]))));
        }
    }

    // contiguous 8-float store per thread (two float4s), coalesced across octets
    float* gout = Gp + ((size_t)kc * NTOK + token) * NEXP + g * 8;
    float4 o0 = make_float4(acc[0], acc[1], acc[2], acc[3]);
    float4 o1 = make_float4(acc[4], acc[5], acc[6], acc[7]);
    *reinterpret_cast<float4*>(gout)     = o0;
    *reinterpret_cast<float4*>(gout + 4) = o1;
    if (g == 0) Cp[(size_t)kc * NTOK + token] = ss;
}

// ---------------------------------------------------------------------------
// Kernel 3: finalize.  One wave per token, lane = expert.
// logit = -sqrt(||x||^2 - 2 G + ||w||^2); top-2 (lower-index tie-break, like
// lax.top_k); softmax over the two; scatter. grid = NTOK/4, block = 256.
// ---------------------------------------------------------------------------
__global__ __launch_bounds__(256) void finalize(const float* __restrict__ Gp,
                                                const float* __restrict__ Cp,
                                                const float* __restrict__ nrm,
                                                float* __restrict__ out) {
    const int wv = threadIdx.x >> 6, lane = threadIdx.x & 63;
    const int token = blockIdx.x * 4 + wv;

    float gsum = 0.f;
    #pragma unroll
    for (int c = 0; c < NKC; ++c)
        gsum += Gp[((size_t)c * NTOK + token) * NEXP + lane];
    float csum = 0.f;
    #pragma unroll
    for (int c = 0; c < NKC; ++c)
        csum += Cp[(size_t)c * NTOK + token];

    const float S = fmaf(-2.f, gsum, csum) + nrm[lane];
    const float logit = -sqrtf(S);

    // top-1
    float v1 = logit; int i1 = lane;
    #pragma unroll
    for (int off = 32; off > 0; off >>= 1) {
        float ov = __shfl_xor(v1, off, 64);
        int   oi = __shfl_xor(i1, off, 64);
        if (ov > v1 || (ov == v1 && oi < i1)) { v1 = ov; i1 = oi; }
    }
    // top-2 (exclude i1)
    float v2 = (lane == i1) ? -__builtin_inff() : logit;
    int   i2 = lane;
    #pragma unroll
    for (int off = 32; off > 0; off >>= 1) {
        float ov = __shfl_xor(v2, off, 64);
        int   oi = __shfl_xor(i2, off, 64);
        if (ov > v2 || (ov == v2 && oi < i2)) { v2 = ov; i2 = oi; }
    }

    const float e2  = expf(v2 - v1);          // <= 1
    const float inv = 1.f / (1.f + e2);
    const float o = (lane == i1) ? inv : ((lane == i2) ? e2 * inv : 0.f);
    out[(size_t)token * NEXP + lane] = o;
}

// ---------------------------------------------------------------------------
extern "C" void kernel_launch(void* const* d_in, const int* in_sizes, int n_in,
                              void* d_out, int out_size, void* d_ws, size_t ws_size,
                              hipStream_t stream) {
    const float* t1 = (const float*)d_in[0];
    const float* t2 = (const float*)d_in[1];
    const float* W  = (const float*)d_in[2];
    float* out = (float*)d_out;

    char* ws = (char*)d_ws;
    float* Gp  = (float*)ws;                                            // NKC*NTOK*NEXP floats (4 MB)
    float* Cp  = (float*)(ws + (size_t)NKC * NTOK * NEXP * sizeof(float));   // NKC*NTOK floats (64 KB)
    float* nrm = (float*)(ws + (size_t)NKC * NTOK * NEXP * sizeof(float)
                             + (size_t)NKC * NTOK * sizeof(float));          // NEXP floats

    expert_norms<<<NEXP, 256, 0, stream>>>(W, nrm);
    dist_gemm<<<dim3(NTOK / TB, NKC), 256, 0, stream>>>(t1, t2, W, Gp, Cp);
    finalize<<<NTOK / 4, 256, 0, stream>>>(Gp, Cp, nrm, out);
}

// Round 2
// 210.646 us; speedup vs baseline: 1.4540x; 1.4540x over previous
//
#include <hip/hip_runtime.h>
#include <math.h>

#define NTOK 4096    // tokens (B)
#define NDIM 1024    // per-tensor feature dim (D)
#define NEXP 64      // experts (E)
#define KC   64      // k per LDS stage (per half)
#define NSTAGE 16    // 1024 / KC
#define WSTR (KC + 4) // 68-float row stride: quad bank-group (e+q)%8, uniform
#define TPW  8       // tokens per wave

// ---------------------------------------------------------------------------
// Kernel 1: per-expert squared norms ||w_e||^2  (64 blocks x 256 threads)
// ---------------------------------------------------------------------------
__global__ __launch_bounds__(256) void expert_norms(const float* __restrict__ W,
                                                    float* __restrict__ nrm) {
    const int e = blockIdx.x;
    const float* row = W + (size_t)e * (2 * NDIM);
    float s = 0.f;
    for (int k = threadIdx.x * 4; k < 2 * NDIM; k += 256 * 4) {
        float4 v = *reinterpret_cast<const float4*>(row + k);
        s = fmaf(v.x, v.x, fmaf(v.y, v.y, fmaf(v.z, v.z, fmaf(v.w, v.w, s))));
    }
    #pragma unroll
    for (int off = 32; off > 0; off >>= 1) s += __shfl_down(s, off, 64);
    __shared__ float red[4];
    const int lane = threadIdx.x & 63, wv = threadIdx.x >> 6;
    if (lane == 0) red[wv] = s;
    __syncthreads();
    if (threadIdx.x == 0) nrm[e] = (red[0] + red[1]) + (red[2] + red[3]);
}

// ---------------------------------------------------------------------------
// Kernel 2: fused distance-GEMM + top-2 softmax scatter.
// Block = 256 threads = 4 waves. Wave w: token octet g = w&1, K-half h = w>>1.
// lane = expert. W chunk staged in LDS (register-prefetch pipelined);
// x accessed through wave-uniform pointers (scalar-load friendly).
// Grid = NTOK/16 = 256 blocks.
// ---------------------------------------------------------------------------
__global__ __launch_bounds__(256) void fused_gate(const float* __restrict__ t1,
                                                  const float* __restrict__ t2,
                                                  const float* __restrict__ W,
                                                  const float* __restrict__ nrm,
                                                  float* __restrict__ out) {
    __shared__ float Wl[2 * 64 * WSTR];      // [half][expert][k], padded rows
    __shared__ float comb[2][TPW][NEXP];     // h=1 partial dots
    __shared__ float cs1[2][TPW];            // h=1 ||x||^2 partials

    const int tid  = threadIdx.x;
    const int lane = tid & 63;
    const int g = __builtin_amdgcn_readfirstlane((tid >> 6) & 1);
    const int h = __builtin_amdgcn_readfirstlane(tid >> 7);
    const int tok0 = blockIdx.x * 16 + g * TPW;
    const float* __restrict__ xbase = h ? t2 : t1;   // wave-uniform

    // staging role (independent of compute role): region r, row e, half-row p
    const int r = tid >> 7;
    const int e = (tid & 127) >> 1;
    const int p = tid & 1;
    const float* gsrc0 = W + (size_t)e * (2 * NDIM) + (size_t)r * NDIM + p * 32;
    float* ldst = Wl + (r * 64 + e) * WSTR + p * 32;

    // preload stage 0 into registers
    float4 pre[8];
    #pragma unroll
    for (int j = 0; j < 8; ++j) pre[j] = *reinterpret_cast<const float4*>(gsrc0 + j * 4);

    float acc[TPW];
    #pragma unroll
    for (int t = 0; t < TPW; ++t) acc[t] = 0.f;

    const float* wl = Wl + (h * 64 + lane) * WSTR;

    for (int s = 0; s < NSTAGE; ++s) {
        // commit prefetched stage to LDS (prev compute finished at loop-tail sync)
        #pragma unroll
        for (int j = 0; j < 8; ++j) *reinterpret_cast<float4*>(ldst + j * 4) = pre[j];
        __syncthreads();
        // issue next stage's global loads; they fly during compute below
        if (s + 1 < NSTAGE) {
            const float* gsrc = gsrc0 + (size_t)(s + 1) * KC;
            #pragma unroll
            for (int j = 0; j < 8; ++j) pre[j] = *reinterpret_cast<const float4*>(gsrc + j * 4);
        }
        const float* xs = xbase + (size_t)tok0 * NDIM + s * KC;  // wave-uniform
        #pragma unroll
        for (int k = 0; k < KC; k += 4) {
            float4 wq = *reinterpret_cast<const float4*>(wl + k);
            #pragma unroll
            for (int t = 0; t < TPW; ++t) {
                float4 xq = *reinterpret_cast<const float4*>(xs + (size_t)t * NDIM + k);
                acc[t] = fmaf(xq.x, wq.x, fmaf(xq.y, wq.y,
                          fmaf(xq.z, wq.z, fmaf(xq.w, wq.w, acc[t]))));
            }
        }
        __syncthreads();
    }

    // cooperative ||x_half||^2 per token (coalesced vector loads, L2-hot)
    float cs[TPW];
    #pragma unroll
    for (int t = 0; t < TPW; ++t) {
        const float* xr = xbase + (size_t)(tok0 + t) * NDIM + lane * 16;
        float ss = 0.f;
        #pragma unroll
        for (int j = 0; j < 16; j += 4) {
            float4 v = *reinterpret_cast<const float4*>(xr + j);
            ss = fmaf(v.x, v.x, fmaf(v.y, v.y, fmaf(v.z, v.z, fmaf(v.w, v.w, ss))));
        }
        #pragma unroll
        for (int off = 32; off > 0; off >>= 1) ss += __shfl_xor(ss, off, 64);
        cs[t] = ss;
    }

    if (h == 1) {
        #pragma unroll
        for (int t = 0; t < TPW; ++t) comb[g][t][lane] = acc[t];
        if (lane == 0) {
            #pragma unroll
            for (int t = 0; t < TPW; ++t) cs1[g][t] = cs[t];
        }
    }
    __syncthreads();

    if (h == 0) {
        const float nv = nrm[lane];
        #pragma unroll
        for (int t = 0; t < TPW; ++t) {
            const float dot = acc[t] + comb[g][t][lane];
            const float S = fmaf(-2.f, dot, cs[t] + cs1[g][t]) + nv;
            const float logit = -sqrtf(S);
            // top-1 (lower-index tie-break, matches lax.top_k)
            float v1 = logit; int i1 = lane;
            #pragma unroll
            for (int off = 32; off > 0; off >>= 1) {
                float ov = __shfl_xor(v1, off, 64);
                int   oi = __shfl_xor(i1, off, 64);
                if (ov > v1 || (ov == v1 && oi < i1)) { v1 = ov; i1 = oi; }
            }
            // top-2 (exclude i1)
            float v2 = (lane == i1) ? -__builtin_inff() : logit;
            int   i2 = lane;
            #pragma unroll
            for (int off = 32; off > 0; off >>= 1) {
                float ov = __shfl_xor(v2, off, 64);
                int   oi = __shfl_xor(i2, off, 64);
                if (ov > v2 || (ov == v2 && oi < i2)) { v2 = ov; i2 = oi; }
            }
            const float e2  = expf(v2 - v1);
            const float inv = 1.f / (1.f + e2);
            const float o = (lane == i1) ? inv : ((lane == i2) ? e2 * inv : 0.f);
            out[(size_t)(tok0 + t) * NEXP + lane] = o;
        }
    }
}

// ---------------------------------------------------------------------------
extern "C" void kernel_launch(void* const* d_in, const int* in_sizes, int n_in,
                              void* d_out, int out_size, void* d_ws, size_t ws_size,
                              hipStream_t stream) {
    const float* t1 = (const float*)d_in[0];
    const float* t2 = (const float*)d_in[1];
    const float* W  = (const float*)d_in[2];
    float* out = (float*)d_out;
    float* nrm = (float*)d_ws;   // 64 floats

    expert_norms<<<NEXP, 256, 0, stream>>>(W, nrm);
    fused_gate<<<NTOK / 16, 256, 0, stream>>>(t1, t2, W, nrm, out);
}

// Round 3
// 201.542 us; speedup vs baseline: 1.5197x; 1.0452x over previous
//
#include <hip/hip_runtime.h>
#include <math.h>

#define NTOK 4096
#define NDIM 1024
#define KTOT 2048
#define NEXP 64
#define MT   64          // tokens per block tile
#define KB   64          // k per LDS stage
#define WSTR (KB + 4)    // padded LDS row stride (floats)

// ---------------------------------------------------------------------------
// Kernel 1: per-expert squared norms ||w_e||^2
// ---------------------------------------------------------------------------
__global__ __launch_bounds__(256) void expert_norms(const float* __restrict__ W,
                                                    float* __restrict__ nrm) {
    const int e = blockIdx.x;
    const float* row = W + (size_t)e * KTOT;
    float s = 0.f;
    for (int k = threadIdx.x * 4; k < KTOT; k += 256 * 4) {
        float4 v = *reinterpret_cast<const float4*>(row + k);
        s = fmaf(v.x, v.x, fmaf(v.y, v.y, fmaf(v.z, v.z, fmaf(v.w, v.w, s))));
    }
    #pragma unroll
    for (int off = 32; off > 0; off >>= 1) s += __shfl_down(s, off, 64);
    __shared__ float red[4];
    const int lane = threadIdx.x & 63, wv = threadIdx.x >> 6;
    if (lane == 0) red[wv] = s;
    __syncthreads();
    if (threadIdx.x == 0) nrm[e] = (red[0] + red[1]) + (red[2] + red[3]);
}

// ---------------------------------------------------------------------------
// Kernel 2: split-K tiled GEMM.  Block = 64 tokens x 64 experts, K-chunk =
// nstages*64.  Per thread: 4 tokens (tg+16i) x 4 experts (egB*4+j).
// Gp[kc][token][e] partial dots; Cp[kc][token] partial ||x||^2.
// grid = (NTOK/MT, nkc), block = 256.
// ---------------------------------------------------------------------------
__global__ __launch_bounds__(256, 2) void gemm_tile(const float* __restrict__ t1,
                                                    const float* __restrict__ t2,
                                                    const float* __restrict__ W,
                                                    float* __restrict__ Gp,
                                                    float* __restrict__ Cp,
                                                    int nstages) {
    __shared__ float Xl[MT * WSTR];
    __shared__ float Wl[NEXP * WSTR];

    const int tid  = threadIdx.x;
    const int tg   = tid & 15;        // token sub-row
    const int egB  = tid >> 4;        // expert group: experts egB*4..egB*4+3
    const int kc   = blockIdx.y;
    const int kchunk = nstages * KB;
    const int kbase  = kc * kchunk;   // within [0, 2048)
    const int tok0   = blockIdx.x * MT;

    // the whole chunk lies in one tensor (kchunk divides 1024 evenly)
    const float* __restrict__ xsrc = (kbase < NDIM)
        ? (t1 + (size_t)tok0 * NDIM + kbase)
        : (t2 + (size_t)tok0 * NDIM + (kbase - NDIM));
    const float* __restrict__ wsrc = W + kbase;

    // staging role: 16 rows x 16 float4-cols, 4 row-iterations
    const int srow = tid >> 4;        // 0..15
    const int scol = tid & 15;        // 0..15 (float4 col)

    float acc[4][4];
    #pragma unroll
    for (int i = 0; i < 4; ++i)
        #pragma unroll
        for (int j = 0; j < 4; ++j) acc[i][j] = 0.f;
    float ssq = 0.f;
    const int myi = egB & 3;          // which of my 4 tokens I norm-accumulate

    for (int s = 0; s < nstages; ++s) {
        const int koff = s * KB;
        // ---- stage X (64 tokens x 64 k) and W (64 experts x 64 k) ----
        #pragma unroll
        for (int i = 0; i < 4; ++i) {
            const int row = srow + 16 * i;
            float4 xv = *reinterpret_cast<const float4*>(
                xsrc + (size_t)row * NDIM + koff + scol * 4);
            float4 wv = *reinterpret_cast<const float4*>(
                wsrc + (size_t)row * KTOT + koff + scol * 4);
            *reinterpret_cast<float4*>(Xl + row * WSTR + scol * 4) = xv;
            *reinterpret_cast<float4*>(Wl + row * WSTR + scol * 4) = wv;
        }
        __syncthreads();

        // ---- compute ----
        #pragma unroll
        for (int k = 0; k < KB; k += 4) {
            float4 wf[4], xf[4];
            #pragma unroll
            for (int j = 0; j < 4; ++j)
                wf[j] = *reinterpret_cast<const float4*>(Wl + (egB * 4 + j) * WSTR + k);
            #pragma unroll
            for (int i = 0; i < 4; ++i)
                xf[i] = *reinterpret_cast<const float4*>(Xl + (tg + 16 * i) * WSTR + k);
            #pragma unroll
            for (int i = 0; i < 4; ++i)
                #pragma unroll
                for (int j = 0; j < 4; ++j)
                    acc[i][j] = fmaf(xf[i].x, wf[j].x, fmaf(xf[i].y, wf[j].y,
                                 fmaf(xf[i].z, wf[j].z, fmaf(xf[i].w, wf[j].w, acc[i][j]))));
            const float4 xs = xf[myi];
            ssq = fmaf(xs.x, xs.x, fmaf(xs.y, xs.y, fmaf(xs.z, xs.z, fmaf(xs.w, xs.w, ssq))));
        }
        __syncthreads();
    }

    // ---- write partials ----
    #pragma unroll
    for (int i = 0; i < 4; ++i) {
        const int token = tok0 + tg + 16 * i;
        float4 o = make_float4(acc[i][0], acc[i][1], acc[i][2], acc[i][3]);
        *reinterpret_cast<float4*>(Gp + ((size_t)kc * NTOK + token) * NEXP + egB * 4) = o;
    }
    if (egB < 4)  // wave 0 covers all 64 tokens: token = tg + 16*egB, myi == egB
        Cp[(size_t)kc * NTOK + tok0 + tg + 16 * egB] = ssq;
}

// ---------------------------------------------------------------------------
// Kernel 3: finalize. One wave per token, lane = expert.
// ---------------------------------------------------------------------------
__global__ __launch_bounds__(256) void finalize(const float* __restrict__ Gp,
                                                const float* __restrict__ Cp,
                                                const float* __restrict__ nrm,
                                                float* __restrict__ out,
                                                int nkc) {
    const int wv = threadIdx.x >> 6, lane = threadIdx.x & 63;
    const int token = blockIdx.x * 4 + wv;

    float gsum = 0.f, csum = 0.f;
    for (int c = 0; c < nkc; ++c) {
        gsum += Gp[((size_t)c * NTOK + token) * NEXP + lane];
        csum += Cp[(size_t)c * NTOK + token];
    }
    const float S = fmaf(-2.f, gsum, csum) + nrm[lane];
    const float logit = -sqrtf(S);

    float v1 = logit; int i1 = lane;
    #pragma unroll
    for (int off = 32; off > 0; off >>= 1) {
        float ov = __shfl_xor(v1, off, 64);
        int   oi = __shfl_xor(i1, off, 64);
        if (ov > v1 || (ov == v1 && oi < i1)) { v1 = ov; i1 = oi; }
    }
    float v2 = (lane == i1) ? -__builtin_inff() : logit;
    int   i2 = lane;
    #pragma unroll
    for (int off = 32; off > 0; off >>= 1) {
        float ov = __shfl_xor(v2, off, 64);
        int   oi = __shfl_xor(i2, off, 64);
        if (ov > v2 || (ov == v2 && oi < i2)) { v2 = ov; i2 = oi; }
    }
    const float e2  = expf(v2 - v1);
    const float inv = 1.f / (1.f + e2);
    const float o = (lane == i1) ? inv : ((lane == i2) ? e2 * inv : 0.f);
    out[(size_t)token * NEXP + lane] = o;
}

// ---------------------------------------------------------------------------
extern "C" void kernel_launch(void* const* d_in, const int* in_sizes, int n_in,
                              void* d_out, int out_size, void* d_ws, size_t ws_size,
                              hipStream_t stream) {
    const float* t1 = (const float*)d_in[0];
    const float* t2 = (const float*)d_in[1];
    const float* W  = (const float*)d_in[2];
    float* out = (float*)d_out;

    // choose split-K factor by available workspace
    const size_t need8 = ((size_t)8 * NTOK * NEXP + 8 * NTOK + NEXP) * sizeof(float);
    const int nkc = (ws_size >= need8) ? 8 : 4;
    const int nstages = (KTOT / nkc) / KB;   // 4 or 8

    float* Gp  = (float*)d_ws;
    float* Cp  = Gp + (size_t)nkc * NTOK * NEXP;
    float* nrm = Cp + (size_t)nkc * NTOK;

    expert_norms<<<NEXP, 256, 0, stream>>>(W, nrm);
    gemm_tile<<<dim3(NTOK / MT, nkc), 256, 0, stream>>>(t1, t2, W, Gp, Cp, nstages);
    finalize<<<NTOK / 4, 256, 0, stream>>>(Gp, Cp, nrm, out, nkc);
}

// Round 5
// 87.138 us; speedup vs baseline: 3.5148x; 2.3129x over previous
//
#include <hip/hip_runtime.h>
#include <math.h>

#define NTOK 4096
#define NDIM 1024
#define KTOT 2048
#define NEXP 64
#define MT   64          // tokens per block tile
#define KB   64          // fp32 k per LDS stage
#define LSTR 72          // fp16 row stride in LDS (144 B: 16B-aligned, uniform banks)

typedef _Float16 half8 __attribute__((ext_vector_type(8)));
typedef _Float16 half4 __attribute__((ext_vector_type(4)));
typedef float    floatx4 __attribute__((ext_vector_type(4)));

#define XSCALE 16.0f
#define WSCALE 1024.0f
#define INVSCALE (1.0f / (16.0f * 1024.0f))

struct h2pair { _Float16 h, l; };
__device__ __forceinline__ h2pair split2(float v) {
    h2pair r;
    r.h = (_Float16)v;
    r.l = (_Float16)(v - (float)r.h);
    return r;
}

// ---------------------------------------------------------------------------
// Fused split-K MFMA GEMM.  Block = 64 tokens x 64 experts, 4 waves.
// Stages fp32 X/W tiles -> fp16 (hi,lo) pairs in LDS; 3-pass mfma accumulate:
// xh*wh + xl*wh + xh*wl.  Also produces per-token / per-expert sq-norm
// partials from the fp32 staging values.
// grid = (NTOK/MT, nkc), block = 256.
// ---------------------------------------------------------------------------
__global__ __launch_bounds__(256, 2) void gemm_mfma(const float* __restrict__ t1,
                                                    const float* __restrict__ t2,
                                                    const float* __restrict__ W,
                                                    float* __restrict__ Gp,
                                                    float* __restrict__ Cp,
                                                    float* __restrict__ Wp,
                                                    int nstages) {
    __shared__ _Float16 Xh[MT * LSTR], Xl[MT * LSTR];
    __shared__ _Float16 Wh[NEXP * LSTR], Wl[NEXP * LSTR];

    const int tid  = threadIdx.x;
    const int lane = tid & 63;
    const int wv   = tid >> 6;          // wave id: token strip 16*wv..16*wv+15
    const int srow = tid >> 4;          // staging row 0..15
    const int scol = tid & 15;          // staging float4 col 0..15
    const int kc   = blockIdx.y;
    const int kchunk = nstages * KB;
    const int kbase  = kc * kchunk;
    const int tok0   = blockIdx.x * MT;

    const float* __restrict__ xsrc = (kbase < NDIM)
        ? (t1 + (size_t)tok0 * NDIM + kbase)
        : (t2 + (size_t)tok0 * NDIM + (kbase - NDIM));
    const float* __restrict__ wsrc = W + kbase;

    floatx4 acc[4];
    #pragma unroll
    for (int j = 0; j < 4; ++j) { acc[j][0] = 0.f; acc[j][1] = 0.f; acc[j][2] = 0.f; acc[j][3] = 0.f; }
    float ssx[4] = {0.f, 0.f, 0.f, 0.f};
    float ssw[4] = {0.f, 0.f, 0.f, 0.f};

    // fragment read pointers (fp16 units)
    const int frow = lane & 15;         // m / n within fragment
    const int fq   = lane >> 4;         // k quad: k = fq*8 + j
    const _Float16* xh_p = Xh + (16 * wv + frow) * LSTR + fq * 8;
    const _Float16* xl_p = Xl + (16 * wv + frow) * LSTR + fq * 8;

    for (int s = 0; s < nstages; ++s) {
        // ---- stage: load fp32, split to fp16 hi/lo, write LDS ----
        #pragma unroll
        for (int i = 0; i < 4; ++i) {
            const int row = srow + 16 * i;
            const float4 xv = *reinterpret_cast<const float4*>(
                xsrc + (size_t)row * NDIM + s * KB + scol * 4);
            const float4 wq = *reinterpret_cast<const float4*>(
                wsrc + (size_t)row * KTOT + s * KB + scol * 4);
            ssx[i] = fmaf(xv.x, xv.x, fmaf(xv.y, xv.y, fmaf(xv.z, xv.z, fmaf(xv.w, xv.w, ssx[i]))));
            ssw[i] = fmaf(wq.x, wq.x, fmaf(wq.y, wq.y, fmaf(wq.z, wq.z, fmaf(wq.w, wq.w, ssw[i]))));
            const h2pair x0 = split2(xv.x * XSCALE), x1 = split2(xv.y * XSCALE);
            const h2pair x2 = split2(xv.z * XSCALE), x3 = split2(xv.w * XSCALE);
            const h2pair w0 = split2(wq.x * WSCALE), w1 = split2(wq.y * WSCALE);
            const h2pair w2 = split2(wq.z * WSCALE), w3 = split2(wq.w * WSCALE);
            half4 hx, lx, hw, lw;
            hx[0] = x0.h; hx[1] = x1.h; hx[2] = x2.h; hx[3] = x3.h;
            lx[0] = x0.l; lx[1] = x1.l; lx[2] = x2.l; lx[3] = x3.l;
            hw[0] = w0.h; hw[1] = w1.h; hw[2] = w2.h; hw[3] = w3.h;
            lw[0] = w0.l; lw[1] = w1.l; lw[2] = w2.l; lw[3] = w3.l;
            *reinterpret_cast<half4*>(Xh + row * LSTR + scol * 4) = hx;
            *reinterpret_cast<half4*>(Xl + row * LSTR + scol * 4) = lx;
            *reinterpret_cast<half4*>(Wh + row * LSTR + scol * 4) = hw;
            *reinterpret_cast<half4*>(Wl + row * LSTR + scol * 4) = lw;
        }
        __syncthreads();

        // ---- compute: 2 K-steps of 32, 3 passes (hh, lh, hl) ----
        #pragma unroll
        for (int ks = 0; ks < 2; ++ks) {
            const int ko = ks * 32;
            const half8 ah = *reinterpret_cast<const half8*>(xh_p + ko);
            const half8 al = *reinterpret_cast<const half8*>(xl_p + ko);
            half8 bh[4], bl[4];
            #pragma unroll
            for (int j = 0; j < 4; ++j) {
                bh[j] = *reinterpret_cast<const half8*>(Wh + (16 * j + frow) * LSTR + fq * 8 + ko);
                bl[j] = *reinterpret_cast<const half8*>(Wl + (16 * j + frow) * LSTR + fq * 8 + ko);
            }
            #pragma unroll
            for (int j = 0; j < 4; ++j)
                acc[j] = __builtin_amdgcn_mfma_f32_16x16x32_f16(ah, bh[j], acc[j], 0, 0, 0);
            #pragma unroll
            for (int j = 0; j < 4; ++j)
                acc[j] = __builtin_amdgcn_mfma_f32_16x16x32_f16(al, bh[j], acc[j], 0, 0, 0);
            #pragma unroll
            for (int j = 0; j < 4; ++j)
                acc[j] = __builtin_amdgcn_mfma_f32_16x16x32_f16(ah, bl[j], acc[j], 0, 0, 0);
        }
        __syncthreads();
    }

    // ---- write dot partials (C/D layout: col=lane&15, row=(lane>>4)*4+reg) ----
    const int m0 = 16 * wv + fq * 4;
    #pragma unroll
    for (int j = 0; j < 4; ++j) {
        #pragma unroll
        for (int i = 0; i < 4; ++i) {
            Gp[((size_t)kc * NTOK + tok0 + m0 + i) * NEXP + 16 * j + frow] = acc[j][i] * INVSCALE;
        }
    }

    // ---- norm partials: reduce across the 16 staging lanes of each row ----
    #pragma unroll
    for (int off = 1; off < 16; off <<= 1) {
        #pragma unroll
        for (int i = 0; i < 4; ++i) {
            ssx[i] += __shfl_xor(ssx[i], off, 64);
            ssw[i] += __shfl_xor(ssw[i], off, 64);
        }
    }
    if (scol == 0) {
        #pragma unroll
        for (int i = 0; i < 4; ++i)
            Cp[(size_t)kc * NTOK + tok0 + srow + 16 * i] = ssx[i];
        if (blockIdx.x == 0) {
            #pragma unroll
            for (int i = 0; i < 4; ++i)
                Wp[kc * NEXP + srow + 16 * i] = ssw[i];
        }
    }
}

// ---------------------------------------------------------------------------
// Finalize: one wave per token, lane = expert.  Sums split-K partials,
// logit = -sqrt(||x||^2 - 2 dot + ||w||^2), top-2 softmax scatter.
// ---------------------------------------------------------------------------
__global__ __launch_bounds__(256) void finalize(const float* __restrict__ Gp,
                                                const float* __restrict__ Cp,
                                                const float* __restrict__ Wp,
                                                float* __restrict__ out,
                                                int nkc) {
    const int wv = threadIdx.x >> 6, lane = threadIdx.x & 63;
    const int token = blockIdx.x * 4 + wv;

    float gsum = 0.f, csum = 0.f, nv = 0.f;
    for (int c = 0; c < nkc; ++c) {
        gsum += Gp[((size_t)c * NTOK + token) * NEXP + lane];
        csum += Cp[(size_t)c * NTOK + token];
        nv   += Wp[c * NEXP + lane];
    }
    const float S = fmaf(-2.f, gsum, csum) + nv;
    const float logit = -sqrtf(S);

    float v1 = logit; int i1 = lane;
    #pragma unroll
    for (int off = 32; off > 0; off >>= 1) {
        float ov = __shfl_xor(v1, off, 64);
        int   oi = __shfl_xor(i1, off, 64);
        if (ov > v1 || (ov == v1 && oi < i1)) { v1 = ov; i1 = oi; }
    }
    float v2 = (lane == i1) ? -__builtin_inff() : logit;
    int   i2 = lane;
    #pragma unroll
    for (int off = 32; off > 0; off >>= 1) {
        float ov = __shfl_xor(v2, off, 64);
        int   oi = __shfl_xor(i2, off, 64);
        if (ov > v2 || (ov == v2 && oi < i2)) { v2 = ov; i2 = oi; }
    }
    const float e2  = expf(v2 - v1);
    const float inv = 1.f / (1.f + e2);
    const float o = (lane == i1) ? inv : ((lane == i2) ? e2 * inv : 0.f);
    out[(size_t)token * NEXP + lane] = o;
}

// ---------------------------------------------------------------------------
extern "C" void kernel_launch(void* const* d_in, const int* in_sizes, int n_in,
                              void* d_out, int out_size, void* d_ws, size_t ws_size,
                              hipStream_t stream) {
    const float* t1 = (const float*)d_in[0];
    const float* t2 = (const float*)d_in[1];
    const float* W  = (const float*)d_in[2];
    float* out = (float*)d_out;

    const size_t need8 = ((size_t)8 * NTOK * NEXP + 8 * NTOK + 8 * NEXP) * sizeof(float);
    const int nkc = (ws_size >= need8) ? 8 : 4;
    const int nstages = (KTOT / nkc) / KB;   // 4 or 8

    float* Gp = (float*)d_ws;
    float* Cp = Gp + (size_t)nkc * NTOK * NEXP;
    float* Wp = Cp + (size_t)nkc * NTOK;

    gemm_mfma<<<dim3(NTOK / MT, nkc), 256, 0, stream>>>(t1, t2, W, Gp, Cp, Wp, nstages);
    finalize<<<NTOK / 4, 256, 0, stream>>>(Gp, Cp, Wp, out, nkc);
}